// Round 20
// baseline (390.927 us; speedup 1.0000x reference)
//
#include <hip/hip_runtime.h>
#include <stdint.h>

using u16 = unsigned short;
using u32 = unsigned int;

typedef __bf16 bf16x8 __attribute__((ext_vector_type(8)));
typedef float f32x4 __attribute__((ext_vector_type(4)));
typedef u16 u16x8 __attribute__((ext_vector_type(8)));

__device__ __forceinline__ u16 f2bf(float f){
  u32 u = __float_as_uint(f);
  return (u16)((u + 0x7FFFu + ((u >> 16) & 1u)) >> 16);
}
__device__ __forceinline__ float bf2f(u16 h){
  return __uint_as_float(((u32)h) << 16);
}
__device__ __forceinline__ void split2(float x, u16& hi, u16& lo){
  hi = f2bf(x);
  lo = f2bf(x - bf2f(hi));
}
template<int SH>
__device__ __forceinline__ int swz(int off){ return off ^ (((off >> SH) & 7) << 4); }

// async global->LDS, 16B per lane; LDS dest must be wave-uniform
__device__ __forceinline__ void gload16(const u16* g, u16* l){
  __builtin_amdgcn_global_load_lds(
      (const __attribute__((address_space(1))) void*)g,
      (__attribute__((address_space(3))) void*)l, 16, 0, 0);
}

// ------- fused fp32 -> (hi,lo) bf16 split for x | qkv_w | proj_w ------------
__global__ __launch_bounds__(256) void k_split3(
    const float* __restrict__ x,  u16* __restrict__ xh,  u16* __restrict__ xl,
    const float* __restrict__ w,  u16* __restrict__ wh,  u16* __restrict__ wl,
    const float* __restrict__ p,  u16* __restrict__ ph,  u16* __restrict__ pl)
{
  int bb = blockIdx.x;
  const float* src; u16* hi; u16* lo; int base;
  if (bb < 6144){ src = x; hi = xh; lo = xl; base = bb; }
  else if (bb < 7872){ src = w; hi = wh; lo = wl; base = bb - 6144; }
  else { src = p; hi = ph; lo = pl; base = bb - 7872; }
  int i = base * 256 + threadIdx.x;
  float4 v = ((const float4*)src)[i];
  ushort4 h, l;
  split2(v.x, h.x, l.x);
  split2(v.y, h.y, l.y);
  split2(v.z, h.z, l.z);
  split2(v.w, h.w, l.w);
  ((ushort4*)hi)[i] = h;
  ((ushort4*)lo)[i] = l;
}

// ------- bias precompute in MFMA-FRAGMENT order -----------------------------
__global__ __launch_bounds__(256) void k_bias(const int* __restrict__ relidx,
                                              const float* __restrict__ table,
                                              u16* __restrict__ biasP)
{
  const int q16 = blockIdx.x;            // 0..63
  const int jt  = blockIdx.y;            // 0..15
  const int lane = threadIdx.x & 63;
  const int hg   = threadIdx.x >> 6;     // 0..3 -> h = hg*3 + {0,1,2}
  const int g = lane >> 4, cl = lane & 15;

  int idxs[16];
#pragma unroll
  for (int nf = 0; nf < 4; ++nf)
#pragma unroll
    for (int r = 0; r < 4; ++r)
      idxs[nf * 4 + r] = relidx[(q16 * 16 + g * 4 + r) * 1024 + jt * 64 + nf * 16 + cl];

#pragma unroll
  for (int i = 0; i < 3; ++i){
    int h = hg * 3 + i;
    u16x8 o0, o1;
#pragma unroll
    for (int e = 0; e < 8; ++e)  o0[e] = f2bf(table[(size_t)idxs[e] * 12 + h]);
#pragma unroll
    for (int e = 0; e < 8; ++e)  o1[e] = f2bf(table[(size_t)idxs[8 + e] * 12 + h]);
    size_t base = ((((size_t)h * 64 + q16) * 16 + jt) * 64 + lane) * 16;
    *(u16x8*)(biasP + base)     = o0;
    *(u16x8*)(biasP + base + 8) = o1;
  }
}

// =============== 256x256-tile QKV GEMM (r17: single barrier per K-tile) ======
__global__ __launch_bounds__(512) void k_g256(
    const u16* __restrict__ A0, const u16* __restrict__ A1, const u16* __restrict__ A2,
    const u16* __restrict__ B0, const u16* __restrict__ B1, const u16* __restrict__ B2,
    const float* __restrict__ bq, const float* __restrict__ bv,
    u16* __restrict__ QKhi, u16* __restrict__ QKlo,
    u16* __restrict__ Vthi, u16* __restrict__ Vtlo)
{
  extern __shared__ u16 R[];                 // [4 slots][A 8192 | B 8192] u16
  const int tid = threadIdx.x;
  const int lane = tid & 63;
  const int wid = tid >> 6;                  // 0..7
  const int wm = wid >> 2, wn = wid & 3;     // 2M x 4N wave grid
  const int g = lane >> 4, cl = lane & 15;
  // T1: XCD-chunked bijective swizzle (nwg = 288, %8 == 0)
  const int orig = blockIdx.y * gridDim.x + blockIdx.x;
  const int cpx = (gridDim.x * gridDim.y) >> 3;
  const int wg = (orig & 7) * cpx + (orig >> 3);
  const int bx = wg % gridDim.x, by = wg / gridDim.x;
  const int bm = by << 8, bn = bx << 8;
  const int rlane = lane >> 2;               // 0..15 row within 16-row run
  const int csrc = (lane & 3) ^ ((lane >> 3) & 3);  // pre-swizzled k-chunk

  f32x4 acc[8][4];
  f32x4 z4 = {0.f, 0.f, 0.f, 0.f};
#pragma unroll
  for (int i = 0; i < 8; ++i)
#pragma unroll
    for (int j = 0; j < 4; ++j) acc[i][j] = z4;

  auto stageA = [&](int t){
    int tt = (t < 72) ? t : t - 72;
    int ph = (tt >= 48) ? 2 : ((tt >= 24) ? 1 : 0);
    int kin = (tt - ph * 24) * 32;
    const u16* Ap = ph == 0 ? A0 : (ph == 1 ? A1 : A2);
    const int sb = (t & 3) * 16384;
#pragma unroll
    for (int i = 0; i < 2; ++i){
      int rA = (wid * 2 + i) * 16 + rlane;   // 0..255
      gload16(Ap + (size_t)(bm + rA) * 768 + kin + csrc * 8,
              &R[sb + (wid * 2 + i) * 512]);
    }
  };
  auto stageB = [&](int t){
    int tt = (t < 72) ? t : t - 72;
    int ph = (tt >= 48) ? 2 : ((tt >= 24) ? 1 : 0);
    int kin = (tt - ph * 24) * 32;
    const u16* Bp = ph == 0 ? B0 : (ph == 1 ? B1 : B2);
    const int sb = (t & 3) * 16384 + 8192;
#pragma unroll
    for (int i = 0; i < 2; ++i){
      int rB = (wid * 2 + i) * 16 + rlane;
      gload16(Bp + (size_t)(bn + rB) * 768 + kin + csrc * 8,
              &R[sb + (wid * 2 + i) * 512]);
    }
  };
  auto rf = [&](const u16* base, int row) -> bf16x8 {
    return *(const bf16x8*)(base + row * 32 + ((g ^ ((cl >> 1) & 3)) << 3));
  };

  stageA(0); stageB(0); stageA(1); stageB(1); stageA(2); stageB(2);  // 12 loads

  for (int t = 0; t < 72; ++t){
    asm volatile("s_waitcnt vmcnt(8)" ::: "memory");   // tile t landed
    __builtin_amdgcn_s_barrier();                      // ONLY barrier per tile
    __builtin_amdgcn_sched_barrier(0);
    const u16* Ab = &R[(t & 3) * 16384];
    const u16* Bb = Ab + 8192;
    // ---- phase 0: mf 0..3 ----
    stageA(t + 3);
    bf16x8 bfv[4], af[4];
#pragma unroll
    for (int nf = 0; nf < 4; ++nf) bfv[nf] = rf(Bb, wn * 64 + nf * 16 + cl);
#pragma unroll
    for (int mf = 0; mf < 4; ++mf) af[mf] = rf(Ab, wm * 128 + mf * 16 + cl);
    asm volatile("s_waitcnt lgkmcnt(0)" ::: "memory");
    __builtin_amdgcn_sched_barrier(0);
    __builtin_amdgcn_s_setprio(1);
#pragma unroll
    for (int mf = 0; mf < 4; ++mf)
#pragma unroll
      for (int nf = 0; nf < 4; ++nf)
        acc[mf][nf] = __builtin_amdgcn_mfma_f32_16x16x32_bf16(af[mf], bfv[nf], acc[mf][nf], 0, 0, 0);
    __builtin_amdgcn_s_setprio(0);
    __builtin_amdgcn_sched_barrier(0);
    // ---- phase 1: mf 4..7 (B frags reused; no barrier needed) ----
    stageB(t + 3);
#pragma unroll
    for (int mf = 0; mf < 4; ++mf) af[mf] = rf(Ab, wm * 128 + (mf + 4) * 16 + cl);
    asm volatile("s_waitcnt lgkmcnt(0)" ::: "memory");
    __builtin_amdgcn_sched_barrier(0);
    __builtin_amdgcn_s_setprio(1);
#pragma unroll
    for (int mf = 0; mf < 4; ++mf)
#pragma unroll
      for (int nf = 0; nf < 4; ++nf)
        acc[mf + 4][nf] = __builtin_amdgcn_mfma_f32_16x16x32_bf16(af[mf], bfv[nf], acc[mf + 4][nf], 0, 0, 0);
    __builtin_amdgcn_s_setprio(0);
  }

  // ================= epilogue (drains prefetch via __syncthreads) ============
  const int bb = bm >> 10;
  const int tokb = bm & 1023;                // 1024 % 256 == 0: no crossing
  u16* Hs = R;                               // [32][256] u16, 16 KB
  u16* Ls = R + 8192;

  if (bx < 6){
    // ---- Q/K -> flat [8192][1536]; 8 chunks of 32 rows ----
    const bool isQ = (bx < 3);
#pragma unroll
    for (int c = 0; c < 8; ++c){
      __syncthreads();
      if (wm == (c >> 2)){
#pragma unroll
        for (int mi = 0; mi < 2; ++mi){
          const int mf = (c & 3) * 2 + mi;
#pragma unroll
          for (int nf = 0; nf < 4; ++nf){
            int col = wn * 64 + nf * 16 + cl;        // 0..255
            float bqv = isQ ? bq[bn + col] : 0.f;
#pragma unroll
            for (int r = 0; r < 4; ++r){
              float v = acc[mf][nf][r];
              if (isQ) v = (v + bqv) * 0.125f;
              u16 hi, lo; split2(v, hi, lo);
              int idx = (mi * 16 + g * 4 + r) * 256 + col;
              Hs[idx] = hi;
              Ls[idx] = lo;
            }
          }
        }
      }
      __syncthreads();
#pragma unroll
      for (int i = 0; i < 2; ++i){
        int s = tid + i * 512;
        int rr = s >> 5, seg = s & 31;
        size_t gb = (size_t)(bm + c * 32 + rr) * 1536 + bn + seg * 8;
        *(float4*)(QKhi + gb) = *(const float4*)(Hs + rr * 256 + seg * 8);
        *(float4*)(QKlo + gb) = *(const float4*)(Ls + rr * 256 + seg * 8);
      }
    }
  } else {
    // ---- V -> V^T (b,h,d,n); 8 chunks of 32 cols, [32 cols][256 m] ----
    const int ccolbase = bn - 1536;
#pragma unroll
    for (int c = 0; c < 8; ++c){
      __syncthreads();
      if (wn == (c >> 1)){
#pragma unroll
        for (int nf2 = 0; nf2 < 2; ++nf2){
          const int nf = (c & 1) * 2 + nf2;
          int cc = nf2 * 16 + cl;                    // 0..31 within chunk
          float bvv = bv[ccolbase + c * 32 + cc];
#pragma unroll
          for (int mf = 0; mf < 8; ++mf){
            ushort4 h4, l4;
            u16 hh_, ll_;
            split2(acc[mf][nf][0] + bvv, hh_, ll_); h4.x = hh_; l4.x = ll_;
            split2(acc[mf][nf][1] + bvv, hh_, ll_); h4.y = hh_; l4.y = ll_;
            split2(acc[mf][nf][2] + bvv, hh_, ll_); h4.z = hh_; l4.z = ll_;
            split2(acc[mf][nf][3] + bvv, hh_, ll_); h4.w = hh_; l4.w = ll_;
            int m0 = wm * 128 + mf * 16 + g * 4;
            int off = cc * 512 + m0 * 2;             // bytes, 8B-aligned
            *(ushort4*)((char*)Hs + swz<9>(off)) = h4;
            *(ushort4*)((char*)Ls + swz<9>(off)) = l4;
          }
        }
      }
      __syncthreads();
#pragma unroll
      for (int i = 0; i < 2; ++i){
        int s = tid + i * 512;
        int drr = s >> 5, seg = s & 31;
        int off = drr * 512 + seg * 16;
        int ccol = ccolbase + c * 32 + drr;
        int hh = ccol >> 6, d = ccol & 63;
        size_t gb = ((size_t)(bb * 12 + hh) * 64 + d) * 1024 + tokb + seg * 8;
        *(float4*)(Vthi + gb) = *(const float4*)((char*)Hs + swz<9>(off));
        *(float4*)(Vtlo + gb) = *(const float4*)((char*)Ls + swz<9>(off));
      }
    }
  }
}

// ---------------- 128x128 proj GEMM (r12 4-slot ring + T1 swizzle) -----------
__global__ __launch_bounds__(256) void k_proj(
    const u16* __restrict__ A0, const u16* __restrict__ A1, const u16* __restrict__ A2,
    const u16* __restrict__ B0, const u16* __restrict__ B1, const u16* __restrict__ B2,
    const float* __restrict__ pb,
    float* __restrict__ Cout)
{
  __shared__ __align__(16) u16 As[4][128 * 32];
  __shared__ __align__(16) u16 Bs[4][128 * 32];
  const int tid = threadIdx.x;
  const int lane = tid & 63;
  const int wid = tid >> 6;
  const int wr = wid >> 1, wc = wid & 1;
  const int g = lane >> 4, cl = lane & 15;
  // T1 swizzle (nwg = 384, %8 == 0)
  const int orig = blockIdx.y * gridDim.x + blockIdx.x;
  const int cpx = (gridDim.x * gridDim.y) >> 3;
  const int wg = (orig & 7) * cpx + (orig >> 3);
  const int bx = wg % gridDim.x, by = wg / gridDim.x;
  const int bm = by << 7, bn = bx << 7;
  const int srow = lane >> 2;
  const int sseg = ((lane & 3) ^ ((lane >> 3) & 3)) * 8;
  const int gph  = (g ^ ((cl >> 1) & 3)) * 8;

  f32x4 acc[4][4];
  f32x4 z4 = {0.f, 0.f, 0.f, 0.f};
#pragma unroll
  for (int i = 0; i < 4; ++i)
#pragma unroll
    for (int j = 0; j < 4; ++j) acc[i][j] = z4;

  auto stage = [&](int t){
    int tt = (t < 72) ? t : t - 72;
    int ph = (tt >= 48) ? 2 : ((tt >= 24) ? 1 : 0);
    int kin = (tt - ph * 24) * 32;
    const u16* Ap = ph == 0 ? A0 : (ph == 1 ? A1 : A2);
    const u16* Bp = ph == 0 ? B0 : (ph == 1 ? B1 : B2);
    const int slot = t & 3;
#pragma unroll
    for (int c = 0; c < 2; ++c){
      int chunk = wid * 2 + c;
      int row = chunk * 16 + srow;
      gload16(Ap + (size_t)(bm + row) * 768 + kin + sseg, &As[slot][chunk * 512]);
      gload16(Bp + (size_t)(bn + row) * 768 + kin + sseg, &Bs[slot][chunk * 512]);
    }
  };

  stage(0); stage(1); stage(2);
  for (int t = 0; t < 72; ++t){
    asm volatile("s_waitcnt vmcnt(8)" ::: "memory");
    __builtin_amdgcn_s_barrier();
    __builtin_amdgcn_sched_barrier(0);
    stage(t + 3);
    const int slot = t & 3;
    bf16x8 af[4], bfv[4];
#pragma unroll
    for (int mf = 0; mf < 4; ++mf)
      af[mf] = *(const bf16x8*)(&As[slot][(wr * 64 + mf * 16 + cl) * 32 + gph]);
#pragma unroll
    for (int nf = 0; nf < 4; ++nf)
      bfv[nf] = *(const bf16x8*)(&Bs[slot][(wc * 64 + nf * 16 + cl) * 32 + gph]);
    asm volatile("s_waitcnt lgkmcnt(0)" ::: "memory");
    __builtin_amdgcn_sched_barrier(0);
    __builtin_amdgcn_s_setprio(1);
#pragma unroll
    for (int mf = 0; mf < 4; ++mf)
#pragma unroll
      for (int nf = 0; nf < 4; ++nf)
        acc[mf][nf] = __builtin_amdgcn_mfma_f32_16x16x32_bf16(af[mf], bfv[nf], acc[mf][nf], 0, 0, 0);
    __builtin_amdgcn_s_setprio(0);
  }

  __syncthreads();                     // drain leftover prefetch loads
#pragma unroll
  for (int mf = 0; mf < 4; ++mf)
#pragma unroll
    for (int nf = 0; nf < 4; ++nf)
#pragma unroll
      for (int r = 0; r < 4; ++r){
        int m = bm + wr * 64 + mf * 16 + g * 4 + r;
        int n = bn + wc * 64 + nf * 16 + cl;
        Cout[(size_t)m * 768 + n] = acc[mf][nf][r] + pb[n];
      }
}

// ---------------- flash attention: bias-as-accumulator-init + defer-max ------
__global__ __launch_bounds__(256) void k_attn(
    const u16* __restrict__ QKhi, const u16* __restrict__ QKlo,
    const u16* __restrict__ Vthi, const u16* __restrict__ Vtlo,
    const u16* __restrict__ biasP,
    u16* __restrict__ Ohi, u16* __restrict__ Olo)
{
  __shared__ __align__(16) u16 lds[36864];
  const int KH0 = 0, KL0 = 8192, VH0 = 16384, VL0 = 24576, PS = 32768;

  const int tid = threadIdx.x;
  const int lane = tid & 63;
  const int w = tid >> 6;
  const int g = lane >> 4, cl = lane & 15;
  const int qt = blockIdx.x;
  const int b  = blockIdx.y;
  const int h  = blockIdx.z;
  const size_t rowbase = (size_t)b * 1024;
  const size_t bhv = (size_t)(b * 12 + h) * (1024 * 64);
  // fragment-ordered bias: [(h*64+q16)*16 + jt][lane][16]
  const u16* bias_base = biasP + ((size_t)h * 64 + qt * 4 + w) * 16384;

  const int dr = lane >> 3, dc = lane & 7;
  const int csrc = dc ^ dr;
  const size_t kbase = (rowbase + w * 16 + dr) * 1536 + 768 + (size_t)h * 64 + csrc * 8;
  const size_t vbase = bhv + (size_t)(w * 16 + dr) * 1024 + csrc * 8;

  auto stage = [&](int buf, int jt){
#pragma unroll
    for (int i = 0; i < 2; ++i){
      int r0 = (w * 16 + i * 8) * 64;
      size_t ko = kbase + (size_t)(jt * 64 + i * 8) * 1536;
      size_t vo = vbase + (size_t)i * 8 * 1024 + jt * 64;
      gload16(QKhi + ko, &lds[KH0 + buf * 4096 + r0]);
      gload16(QKlo + ko, &lds[KL0 + buf * 4096 + r0]);
      gload16(Vthi + vo, &lds[VH0 + buf * 4096 + r0]);
      gload16(Vtlo + vo, &lds[VL0 + buf * 4096 + r0]);
    }
  };
  auto tread = [&](int base, int r, int cb) -> bf16x8 {
    int byte = r * 128 + ((cb ^ (r & 7)) << 4);
    return *(const bf16x8*)((const char*)&lds[base] + byte);
  };

  bf16x8 aq[4];
  {
    const u16* qh = QKhi + (rowbase + qt * 64 + w * 16 + cl) * 1536 + h * 64;
    const u16* ql = QKlo + (rowbase + qt * 64 + w * 16 + cl) * 1536 + h * 64;
    aq[0] = *(const bf16x8*)(qh + g * 8);
    aq[1] = *(const bf16x8*)(qh + 32 + g * 8);
    aq[2] = *(const bf16x8*)(ql + g * 8);
    aq[3] = *(const bf16x8*)(ql + 32 + g * 8);
  }

  f32x4 o[4];
  float m_run[4], l_run[4];
  f32x4 z4 = {0.f, 0.f, 0.f, 0.f};
#pragma unroll
  for (int nd = 0; nd < 4; ++nd) o[nd] = z4;
#pragma unroll
  for (int r = 0; r < 4; ++r){ m_run[r] = -1e30f; l_run[r] = 0.f; }

  const int AI[6] = {0, 1, 0, 1, 2, 3};
  const int BI[6] = {0, 1, 2, 3, 0, 1};

  stage(0, 0);
  int buf = 0;
  for (int jt = 0; jt < 16; ++jt){
    __syncthreads();
    if (jt + 1 < 16) stage(buf ^ 1, jt + 1);

    // -------- init S accumulators from bias (MFMA C-input does the add) -----
    f32x4 s[4];
    {
      const u16* bp = bias_base + ((jt * 64 + lane) << 4);
      u16x8 b0 = *(const u16x8*)(bp);
      u16x8 b1 = *(const u16x8*)(bp + 8);
#pragma unroll
      for (int r = 0; r < 4; ++r){
        s[0][r] = bf2f(b0[r]);
        s[1][r] = bf2f(b0[4 + r]);
        s[2][r] = bf2f(b1[r]);
        s[3][r] = bf2f(b1[4 + r]);
      }
    }
#pragma unroll
    for (int ks = 0; ks < 6; ++ks){
      const int t = BI[ks];
      const int kb = (t >= 2 ? KL0 : KH0) + buf * 4096;
      const int cb = (t & 1) * 4 + g;
      bf16x8 b4[4];
#pragma unroll
      for (int nf = 0; nf < 4; ++nf)
        b4[nf] = tread(kb, nf * 16 + cl, cb);
#pragma unroll
      for (int nf = 0; nf < 4; ++nf)
        s[nf] = __builtin_amdgcn_mfma_f32_16x16x32_bf16(aq[AI[ks]], b4[nf], s[nf], 0, 0, 0);
    }

    // -------- online softmax with defer-max (T13, THR=8) --------
    float mx4[4];
    float need = -1e30f;
#pragma unroll
    for (int r = 0; r < 4; ++r){
      float mx = fmaxf(fmaxf(s[0][r], s[1][r]), fmaxf(s[2][r], s[3][r]));
      mx = fmaxf(mx, __shfl_xor(mx, 1));
      mx = fmaxf(mx, __shfl_xor(mx, 2));
      mx = fmaxf(mx, __shfl_xor(mx, 4));
      mx = fmaxf(mx, __shfl_xor(mx, 8));
      mx4[r] = mx;
      need = fmaxf(need, mx - m_run[r]);
    }
    if (__any(need > 8.f)){
      // full rescale pass (wave-uniform branch)
#pragma unroll
      for (int r = 0; r < 4; ++r){
        float mn = fmaxf(m_run[r], mx4[r]);
        float fs = __expf(m_run[r] - mn);
        m_run[r] = mn;
        l_run[r] *= fs;
#pragma unroll
        for (int nd = 0; nd < 4; ++nd) o[nd][r] *= fs;
      }
    }
#pragma unroll
    for (int r = 0; r < 4; ++r){
      float rs = 0.f;
#pragma unroll
      for (int nf = 0; nf < 4; ++nf){
        float p = __expf(s[nf][r] - m_run[r]);
        s[nf][r] = p;
        rs += p;
      }
      rs += __shfl_xor(rs, 1);
      rs += __shfl_xor(rs, 2);
      rs += __shfl_xor(rs, 4);
      rs += __shfl_xor(rs, 8);
      l_run[r] += rs;
    }
#pragma unroll
    for (int nf = 0; nf < 4; ++nf)
#pragma unroll
      for (int r = 0; r < 4; ++r){
        int off = (w * 16 + g * 4 + r) * 128 + (nf * 16 + cl) * 2;
        *(u16*)((char*)&lds[PS] + swz<7>(off)) = f2bf(s[nf][r]);
      }

    bf16x8 pa[2];
    {
      int row = (w * 16 + cl) * 128;
      pa[0] = *(const bf16x8*)((char*)&lds[PS] + swz<7>(row + (g * 8) * 2));
      pa[1] = *(const bf16x8*)((char*)&lds[PS] + swz<7>(row + (32 + g * 8) * 2));
    }
#pragma unroll
    for (int ks = 0; ks < 4; ++ks){
      const int vb = (ks < 2 ? VH0 : VL0) + buf * 4096;
      const int cb = (ks & 1) * 4 + g;
      bf16x8 b4[4];
#pragma unroll
      for (int nd = 0; nd < 4; ++nd)
        b4[nd] = tread(vb, nd * 16 + cl, cb);
#pragma unroll
      for (int nd = 0; nd < 4; ++nd)
        o[nd] = __builtin_amdgcn_mfma_f32_16x16x32_bf16(pa[ks & 1], b4[nd], o[nd], 0, 0, 0);
    }
    buf ^= 1;
  }

  __syncthreads();
#pragma unroll
  for (int r = 0; r < 4; ++r){
    float inv = 1.f / l_run[r];
    int row = w * 16 + g * 4 + r;
#pragma unroll
    for (int nd = 0; nd < 4; ++nd){
      u16 hi, lo; split2(o[nd][r] * inv, hi, lo);
      int off = row * 128 + (nd * 16 + cl) * 2;
      *(u16*)((char*)&lds[PS]  + swz<7>(off)) = hi;
      *(u16*)((char*)&lds[KH0] + swz<7>(off)) = lo;
    }
  }
  __syncthreads();
#pragma unroll
  for (int i = 0; i < 2; ++i){
    int s = tid + i * 256;
    int qr = s >> 3;
    int seg = s & 7;
    int off = qr * 128 + seg * 16;
    size_t gb = ((size_t)b * 1024 + qt * 64 + qr) * 768 + h * 64 + seg * 8;
    *(float4*)(Ohi + gb) = *(const float4*)((char*)&lds[PS]  + swz<7>(off));
    *(float4*)(Olo + gb) = *(const float4*)((char*)&lds[KH0] + swz<7>(off));
  }
}

// ---------------------------------------------------------------------------
extern "C" void kernel_launch(void* const* d_in, const int* in_sizes, int n_in,
                              void* d_out, int out_size, void* d_ws, size_t ws_size,
                              hipStream_t stream)
{
  const float* x      = (const float*)d_in[0];
  const float* qkv_w  = (const float*)d_in[1];
  const float* q_bias = (const float*)d_in[2];
  const float* v_bias = (const float*)d_in[3];
  const float* table  = (const float*)d_in[4];
  const float* proj_w = (const float*)d_in[5];
  const float* proj_b = (const float*)d_in[6];
  const int*   relidx = (const int*)d_in[7];
  float* out = (float*)d_out;

  char* ws = (char*)d_ws;
  size_t off = 0;
  auto alloc = [&](size_t nelem) -> u16* {
    u16* p = (u16*)(ws + off);
    off += (nelem * 2 + 255) & ~(size_t)255;
    return p;
  };
  u16* Xhi  = alloc((size_t)8192 * 768);
  u16* Xlo  = alloc((size_t)8192 * 768);
  u16* Whi  = alloc((size_t)2304 * 768);
  u16* Wlo  = alloc((size_t)2304 * 768);
  u16* PWhi = alloc((size_t)768 * 768);
  u16* PWlo = alloc((size_t)768 * 768);
  u16* QKhi = alloc((size_t)8192 * 1536);
  u16* QKlo = alloc((size_t)8192 * 1536);
  u16* Vthi = alloc((size_t)8 * 12 * 64 * 1024);
  u16* Vtlo = alloc((size_t)8 * 12 * 64 * 1024);
  u16* Bias = alloc((size_t)12 * 1024 * 1024);
  // O reuses X space (X consumed by QKV GEMM before attention writes O)
  u16* Ohi = Xhi;
  u16* Olo = Xlo;

  k_split3<<<8448, 256, 0, stream>>>(x, Xhi, Xlo, qkv_w, Whi, Wlo, proj_w, PWhi, PWlo);
  k_bias<<<dim3(64, 16), 256, 0, stream>>>(relidx, table, Bias);

  k_g256<<<dim3(9, 32), 512, 131072, stream>>>(
      Xhi, Xhi, Xlo, Whi, Wlo, Whi,
      q_bias, v_bias,
      QKhi, QKlo, Vthi, Vtlo);

  k_attn<<<dim3(16, 8, 12), 256, 0, stream>>>(
      QKhi, QKlo, Vthi, Vtlo, Bias, Ohi, Olo);

  k_proj<<<dim3(6, 64), 256, 0, stream>>>(
      Ohi, Ohi, Olo, PWhi, PWlo, PWhi,
      proj_b, out);
}

// Round 21
// 386.032 us; speedup vs baseline: 1.0127x; 1.0127x over previous
//
#include <hip/hip_runtime.h>
#include <stdint.h>

using u16 = unsigned short;
using u32 = unsigned int;

typedef __bf16 bf16x8 __attribute__((ext_vector_type(8)));
typedef float f32x4 __attribute__((ext_vector_type(4)));
typedef u16 u16x8 __attribute__((ext_vector_type(8)));

__device__ __forceinline__ u16 f2bf(float f){
  u32 u = __float_as_uint(f);
  return (u16)((u + 0x7FFFu + ((u >> 16) & 1u)) >> 16);
}
__device__ __forceinline__ float bf2f(u16 h){
  return __uint_as_float(((u32)h) << 16);
}
__device__ __forceinline__ void split2(float x, u16& hi, u16& lo){
  hi = f2bf(x);
  lo = f2bf(x - bf2f(hi));
}
template<int SH>
__device__ __forceinline__ int swz(int off){ return off ^ (((off >> SH) & 7) << 4); }

// async global->LDS, 16B per lane; LDS dest must be wave-uniform
__device__ __forceinline__ void gload16(const u16* g, u16* l){
  __builtin_amdgcn_global_load_lds(
      (const __attribute__((address_space(1))) void*)g,
      (__attribute__((address_space(3))) void*)l, 16, 0, 0);
}

// ------- fused fp32 -> (hi,lo) bf16 split for x | qkv_w | proj_w ------------
__global__ __launch_bounds__(256) void k_split3(
    const float* __restrict__ x,  u16* __restrict__ xh,  u16* __restrict__ xl,
    const float* __restrict__ w,  u16* __restrict__ wh,  u16* __restrict__ wl,
    const float* __restrict__ p,  u16* __restrict__ ph,  u16* __restrict__ pl)
{
  int bb = blockIdx.x;
  const float* src; u16* hi; u16* lo; int base;
  if (bb < 6144){ src = x; hi = xh; lo = xl; base = bb; }
  else if (bb < 7872){ src = w; hi = wh; lo = wl; base = bb - 6144; }
  else { src = p; hi = ph; lo = pl; base = bb - 7872; }
  int i = base * 256 + threadIdx.x;
  float4 v = ((const float4*)src)[i];
  ushort4 h, l;
  split2(v.x, h.x, l.x);
  split2(v.y, h.y, l.y);
  split2(v.z, h.z, l.z);
  split2(v.w, h.w, l.w);
  ((ushort4*)hi)[i] = h;
  ((ushort4*)lo)[i] = l;
}

// ------- bias precompute in MFMA-FRAGMENT order -----------------------------
__global__ __launch_bounds__(256) void k_bias(const int* __restrict__ relidx,
                                              const float* __restrict__ table,
                                              u16* __restrict__ biasP)
{
  const int q16 = blockIdx.x;            // 0..63
  const int jt  = blockIdx.y;            // 0..15
  const int lane = threadIdx.x & 63;
  const int hg   = threadIdx.x >> 6;     // 0..3 -> h = hg*3 + {0,1,2}
  const int g = lane >> 4, cl = lane & 15;

  int idxs[16];
#pragma unroll
  for (int nf = 0; nf < 4; ++nf)
#pragma unroll
    for (int r = 0; r < 4; ++r)
      idxs[nf * 4 + r] = relidx[(q16 * 16 + g * 4 + r) * 1024 + jt * 64 + nf * 16 + cl];

#pragma unroll
  for (int i = 0; i < 3; ++i){
    int h = hg * 3 + i;
    u16x8 o0, o1;
#pragma unroll
    for (int e = 0; e < 8; ++e)  o0[e] = f2bf(table[(size_t)idxs[e] * 12 + h]);
#pragma unroll
    for (int e = 0; e < 8; ++e)  o1[e] = f2bf(table[(size_t)idxs[8 + e] * 12 + h]);
    size_t base = ((((size_t)h * 64 + q16) * 16 + jt) * 64 + lane) * 16;
    *(u16x8*)(biasP + base)     = o0;
    *(u16x8*)(biasP + base + 8) = o1;
  }
}

// =============== 256x256-tile QKV GEMM (r17: single barrier per K-tile) ======
__global__ __launch_bounds__(512) void k_g256(
    const u16* __restrict__ A0, const u16* __restrict__ A1, const u16* __restrict__ A2,
    const u16* __restrict__ B0, const u16* __restrict__ B1, const u16* __restrict__ B2,
    const float* __restrict__ bq, const float* __restrict__ bv,
    u16* __restrict__ QKhi, u16* __restrict__ QKlo,
    u16* __restrict__ Vthi, u16* __restrict__ Vtlo)
{
  extern __shared__ u16 R[];                 // [4 slots][A 8192 | B 8192] u16
  const int tid = threadIdx.x;
  const int lane = tid & 63;
  const int wid = tid >> 6;                  // 0..7
  const int wm = wid >> 2, wn = wid & 3;     // 2M x 4N wave grid
  const int g = lane >> 4, cl = lane & 15;
  // T1: XCD-chunked bijective swizzle (nwg = 288, %8 == 0)
  const int orig = blockIdx.y * gridDim.x + blockIdx.x;
  const int cpx = (gridDim.x * gridDim.y) >> 3;
  const int wg = (orig & 7) * cpx + (orig >> 3);
  const int bx = wg % gridDim.x, by = wg / gridDim.x;
  const int bm = by << 8, bn = bx << 8;
  const int rlane = lane >> 2;               // 0..15 row within 16-row run
  const int csrc = (lane & 3) ^ ((lane >> 3) & 3);  // pre-swizzled k-chunk

  f32x4 acc[8][4];
  f32x4 z4 = {0.f, 0.f, 0.f, 0.f};
#pragma unroll
  for (int i = 0; i < 8; ++i)
#pragma unroll
    for (int j = 0; j < 4; ++j) acc[i][j] = z4;

  auto stageA = [&](int t){
    int tt = (t < 72) ? t : t - 72;
    int ph = (tt >= 48) ? 2 : ((tt >= 24) ? 1 : 0);
    int kin = (tt - ph * 24) * 32;
    const u16* Ap = ph == 0 ? A0 : (ph == 1 ? A1 : A2);
    const int sb = (t & 3) * 16384;
#pragma unroll
    for (int i = 0; i < 2; ++i){
      int rA = (wid * 2 + i) * 16 + rlane;   // 0..255
      gload16(Ap + (size_t)(bm + rA) * 768 + kin + csrc * 8,
              &R[sb + (wid * 2 + i) * 512]);
    }
  };
  auto stageB = [&](int t){
    int tt = (t < 72) ? t : t - 72;
    int ph = (tt >= 48) ? 2 : ((tt >= 24) ? 1 : 0);
    int kin = (tt - ph * 24) * 32;
    const u16* Bp = ph == 0 ? B0 : (ph == 1 ? B1 : B2);
    const int sb = (t & 3) * 16384 + 8192;
#pragma unroll
    for (int i = 0; i < 2; ++i){
      int rB = (wid * 2 + i) * 16 + rlane;
      gload16(Bp + (size_t)(bn + rB) * 768 + kin + csrc * 8,
              &R[sb + (wid * 2 + i) * 512]);
    }
  };
  auto rf = [&](const u16* base, int row) -> bf16x8 {
    return *(const bf16x8*)(base + row * 32 + ((g ^ ((cl >> 1) & 3)) << 3));
  };

  stageA(0); stageB(0); stageA(1); stageB(1); stageA(2); stageB(2);  // 12 loads

  for (int t = 0; t < 72; ++t){
    asm volatile("s_waitcnt vmcnt(8)" ::: "memory");   // tile t landed
    __builtin_amdgcn_s_barrier();                      // ONLY barrier per tile
    __builtin_amdgcn_sched_barrier(0);
    const u16* Ab = &R[(t & 3) * 16384];
    const u16* Bb = Ab + 8192;
    // ---- phase 0: mf 0..3 ----
    stageA(t + 3);
    bf16x8 bfv[4], af[4];
#pragma unroll
    for (int nf = 0; nf < 4; ++nf) bfv[nf] = rf(Bb, wn * 64 + nf * 16 + cl);
#pragma unroll
    for (int mf = 0; mf < 4; ++mf) af[mf] = rf(Ab, wm * 128 + mf * 16 + cl);
    asm volatile("s_waitcnt lgkmcnt(0)" ::: "memory");
    __builtin_amdgcn_sched_barrier(0);
    __builtin_amdgcn_s_setprio(1);
#pragma unroll
    for (int mf = 0; mf < 4; ++mf)
#pragma unroll
      for (int nf = 0; nf < 4; ++nf)
        acc[mf][nf] = __builtin_amdgcn_mfma_f32_16x16x32_bf16(af[mf], bfv[nf], acc[mf][nf], 0, 0, 0);
    __builtin_amdgcn_s_setprio(0);
    __builtin_amdgcn_sched_barrier(0);
    // ---- phase 1: mf 4..7 (B frags reused; no barrier needed) ----
    stageB(t + 3);
#pragma unroll
    for (int mf = 0; mf < 4; ++mf) af[mf] = rf(Ab, wm * 128 + (mf + 4) * 16 + cl);
    asm volatile("s_waitcnt lgkmcnt(0)" ::: "memory");
    __builtin_amdgcn_sched_barrier(0);
    __builtin_amdgcn_s_setprio(1);
#pragma unroll
    for (int mf = 0; mf < 4; ++mf)
#pragma unroll
      for (int nf = 0; nf < 4; ++nf)
        acc[mf + 4][nf] = __builtin_amdgcn_mfma_f32_16x16x32_bf16(af[mf], bfv[nf], acc[mf + 4][nf], 0, 0, 0);
    __builtin_amdgcn_s_setprio(0);
  }

  // ================= epilogue (drains prefetch via __syncthreads) ============
  const int bb = bm >> 10;
  const int tokb = bm & 1023;                // 1024 % 256 == 0: no crossing
  u16* Hs = R;                               // [32][256] u16, 16 KB
  u16* Ls = R + 8192;

  if (bx < 6){
    // ---- Q/K -> flat [8192][1536]; 8 chunks of 32 rows ----
    const bool isQ = (bx < 3);
#pragma unroll
    for (int c = 0; c < 8; ++c){
      __syncthreads();
      if (wm == (c >> 2)){
#pragma unroll
        for (int mi = 0; mi < 2; ++mi){
          const int mf = (c & 3) * 2 + mi;
#pragma unroll
          for (int nf = 0; nf < 4; ++nf){
            int col = wn * 64 + nf * 16 + cl;        // 0..255
            float bqv = isQ ? bq[bn + col] : 0.f;
#pragma unroll
            for (int r = 0; r < 4; ++r){
              float v = acc[mf][nf][r];
              if (isQ) v = (v + bqv) * 0.125f;
              u16 hi, lo; split2(v, hi, lo);
              int idx = (mi * 16 + g * 4 + r) * 256 + col;
              Hs[idx] = hi;
              Ls[idx] = lo;
            }
          }
        }
      }
      __syncthreads();
#pragma unroll
      for (int i = 0; i < 2; ++i){
        int s = tid + i * 512;
        int rr = s >> 5, seg = s & 31;
        size_t gb = (size_t)(bm + c * 32 + rr) * 1536 + bn + seg * 8;
        *(float4*)(QKhi + gb) = *(const float4*)(Hs + rr * 256 + seg * 8);
        *(float4*)(QKlo + gb) = *(const float4*)(Ls + rr * 256 + seg * 8);
      }
    }
  } else {
    // ---- V -> V^T (b,h,d,n); 8 chunks of 32 cols, [32 cols][256 m] ----
    const int ccolbase = bn - 1536;
#pragma unroll
    for (int c = 0; c < 8; ++c){
      __syncthreads();
      if (wn == (c >> 1)){
#pragma unroll
        for (int nf2 = 0; nf2 < 2; ++nf2){
          const int nf = (c & 1) * 2 + nf2;
          int cc = nf2 * 16 + cl;                    // 0..31 within chunk
          float bvv = bv[ccolbase + c * 32 + cc];
#pragma unroll
          for (int mf = 0; mf < 8; ++mf){
            ushort4 h4, l4;
            u16 hh_, ll_;
            split2(acc[mf][nf][0] + bvv, hh_, ll_); h4.x = hh_; l4.x = ll_;
            split2(acc[mf][nf][1] + bvv, hh_, ll_); h4.y = hh_; l4.y = ll_;
            split2(acc[mf][nf][2] + bvv, hh_, ll_); h4.z = hh_; l4.z = ll_;
            split2(acc[mf][nf][3] + bvv, hh_, ll_); h4.w = hh_; l4.w = ll_;
            int m0 = wm * 128 + mf * 16 + g * 4;
            int off = cc * 512 + m0 * 2;             // bytes, 8B-aligned
            *(ushort4*)((char*)Hs + swz<9>(off)) = h4;
            *(ushort4*)((char*)Ls + swz<9>(off)) = l4;
          }
        }
      }
      __syncthreads();
#pragma unroll
      for (int i = 0; i < 2; ++i){
        int s = tid + i * 512;
        int drr = s >> 5, seg = s & 31;
        int off = drr * 512 + seg * 16;
        int ccol = ccolbase + c * 32 + drr;
        int hh = ccol >> 6, d = ccol & 63;
        size_t gb = ((size_t)(bb * 12 + hh) * 64 + d) * 1024 + tokb + seg * 8;
        *(float4*)(Vthi + gb) = *(const float4*)((char*)Hs + swz<9>(off));
        *(float4*)(Vtlo + gb) = *(const float4*)((char*)Ls + swz<9>(off));
      }
    }
  }
}

// ---------------- 128x128 proj GEMM (r12 4-slot ring + T1 swizzle) -----------
__global__ __launch_bounds__(256) void k_proj(
    const u16* __restrict__ A0, const u16* __restrict__ A1, const u16* __restrict__ A2,
    const u16* __restrict__ B0, const u16* __restrict__ B1, const u16* __restrict__ B2,
    const float* __restrict__ pb,
    float* __restrict__ Cout)
{
  __shared__ __align__(16) u16 As[4][128 * 32];
  __shared__ __align__(16) u16 Bs[4][128 * 32];
  const int tid = threadIdx.x;
  const int lane = tid & 63;
  const int wid = tid >> 6;
  const int wr = wid >> 1, wc = wid & 1;
  const int g = lane >> 4, cl = lane & 15;
  // T1 swizzle (nwg = 384, %8 == 0)
  const int orig = blockIdx.y * gridDim.x + blockIdx.x;
  const int cpx = (gridDim.x * gridDim.y) >> 3;
  const int wg = (orig & 7) * cpx + (orig >> 3);
  const int bx = wg % gridDim.x, by = wg / gridDim.x;
  const int bm = by << 7, bn = bx << 7;
  const int srow = lane >> 2;
  const int sseg = ((lane & 3) ^ ((lane >> 3) & 3)) * 8;
  const int gph  = (g ^ ((cl >> 1) & 3)) * 8;

  f32x4 acc[4][4];
  f32x4 z4 = {0.f, 0.f, 0.f, 0.f};
#pragma unroll
  for (int i = 0; i < 4; ++i)
#pragma unroll
    for (int j = 0; j < 4; ++j) acc[i][j] = z4;

  auto stage = [&](int t){
    int tt = (t < 72) ? t : t - 72;
    int ph = (tt >= 48) ? 2 : ((tt >= 24) ? 1 : 0);
    int kin = (tt - ph * 24) * 32;
    const u16* Ap = ph == 0 ? A0 : (ph == 1 ? A1 : A2);
    const u16* Bp = ph == 0 ? B0 : (ph == 1 ? B1 : B2);
    const int slot = t & 3;
#pragma unroll
    for (int c = 0; c < 2; ++c){
      int chunk = wid * 2 + c;
      int row = chunk * 16 + srow;
      gload16(Ap + (size_t)(bm + row) * 768 + kin + sseg, &As[slot][chunk * 512]);
      gload16(Bp + (size_t)(bn + row) * 768 + kin + sseg, &Bs[slot][chunk * 512]);
    }
  };

  stage(0); stage(1); stage(2);
  for (int t = 0; t < 72; ++t){
    asm volatile("s_waitcnt vmcnt(8)" ::: "memory");
    __builtin_amdgcn_s_barrier();
    __builtin_amdgcn_sched_barrier(0);
    stage(t + 3);
    const int slot = t & 3;
    bf16x8 af[4], bfv[4];
#pragma unroll
    for (int mf = 0; mf < 4; ++mf)
      af[mf] = *(const bf16x8*)(&As[slot][(wr * 64 + mf * 16 + cl) * 32 + gph]);
#pragma unroll
    for (int nf = 0; nf < 4; ++nf)
      bfv[nf] = *(const bf16x8*)(&Bs[slot][(wc * 64 + nf * 16 + cl) * 32 + gph]);
    asm volatile("s_waitcnt lgkmcnt(0)" ::: "memory");
    __builtin_amdgcn_sched_barrier(0);
    __builtin_amdgcn_s_setprio(1);
#pragma unroll
    for (int mf = 0; mf < 4; ++mf)
#pragma unroll
      for (int nf = 0; nf < 4; ++nf)
        acc[mf][nf] = __builtin_amdgcn_mfma_f32_16x16x32_bf16(af[mf], bfv[nf], acc[mf][nf], 0, 0, 0);
    __builtin_amdgcn_s_setprio(0);
  }

  __syncthreads();                     // drain leftover prefetch loads
#pragma unroll
  for (int mf = 0; mf < 4; ++mf)
#pragma unroll
    for (int nf = 0; nf < 4; ++nf)
#pragma unroll
      for (int r = 0; r < 4; ++r){
        int m = bm + wr * 64 + mf * 16 + g * 4 + r;
        int n = bn + wc * 64 + nf * 16 + cl;
        Cout[(size_t)m * 768 + n] = acc[mf][nf][r] + pb[n];
      }
}

// ---------------- flash attention, QBLK = 64, frag-bias + defer-max ----------
__global__ __launch_bounds__(256) void k_attn(
    const u16* __restrict__ QKhi, const u16* __restrict__ QKlo,
    const u16* __restrict__ Vthi, const u16* __restrict__ Vtlo,
    const u16* __restrict__ biasP,
    u16* __restrict__ Ohi, u16* __restrict__ Olo)
{
  __shared__ __align__(16) u16 lds[36864];
  const int KH0 = 0, KL0 = 8192, VH0 = 16384, VL0 = 24576, PS = 32768;

  const int tid = threadIdx.x;
  const int lane = tid & 63;
  const int w = tid >> 6;
  const int g = lane >> 4, cl = lane & 15;
  const int qt = blockIdx.x;
  const int b  = blockIdx.y;
  const int h  = blockIdx.z;
  const size_t rowbase = (size_t)b * 1024;
  const size_t bhv = (size_t)(b * 12 + h) * (1024 * 64);
  // fragment-ordered bias: [(h*64+q16)*16 + jt][lane][16]
  const u16* bias_base = biasP + ((size_t)h * 64 + qt * 4 + w) * 16384;

  const int dr = lane >> 3, dc = lane & 7;
  const int csrc = dc ^ dr;
  const size_t kbase = (rowbase + w * 16 + dr) * 1536 + 768 + (size_t)h * 64 + csrc * 8;
  const size_t vbase = bhv + (size_t)(w * 16 + dr) * 1024 + csrc * 8;

  auto stage = [&](int buf, int jt){
#pragma unroll
    for (int i = 0; i < 2; ++i){
      int r0 = (w * 16 + i * 8) * 64;
      size_t ko = kbase + (size_t)(jt * 64 + i * 8) * 1536;
      size_t vo = vbase + (size_t)i * 8 * 1024 + jt * 64;
      gload16(QKhi + ko, &lds[KH0 + buf * 4096 + r0]);
      gload16(QKlo + ko, &lds[KL0 + buf * 4096 + r0]);
      gload16(Vthi + vo, &lds[VH0 + buf * 4096 + r0]);
      gload16(Vtlo + vo, &lds[VL0 + buf * 4096 + r0]);
    }
  };
  auto tread = [&](int base, int r, int cb) -> bf16x8 {
    int byte = r * 128 + ((cb ^ (r & 7)) << 4);
    return *(const bf16x8*)((const char*)&lds[base] + byte);
  };

  bf16x8 aq[4];
  {
    const u16* qh = QKhi + (rowbase + qt * 64 + w * 16 + cl) * 1536 + h * 64;
    const u16* ql = QKlo + (rowbase + qt * 64 + w * 16 + cl) * 1536 + h * 64;
    aq[0] = *(const bf16x8*)(qh + g * 8);
    aq[1] = *(const bf16x8*)(qh + 32 + g * 8);
    aq[2] = *(const bf16x8*)(ql + g * 8);
    aq[3] = *(const bf16x8*)(ql + 32 + g * 8);
  }

  f32x4 o[4];
  float m_run[4], l_run[4];
  f32x4 z4 = {0.f, 0.f, 0.f, 0.f};
#pragma unroll
  for (int nd = 0; nd < 4; ++nd) o[nd] = z4;
#pragma unroll
  for (int r = 0; r < 4; ++r){ m_run[r] = -1e30f; l_run[r] = 0.f; }

  const int AI[6] = {0, 1, 0, 1, 2, 3};
  const int BI[6] = {0, 1, 2, 3, 0, 1};

  stage(0, 0);
  int buf = 0;
  for (int jt = 0; jt < 16; ++jt){
    __syncthreads();
    if (jt + 1 < 16) stage(buf ^ 1, jt + 1);

    f32x4 s[4];
#pragma unroll
    for (int nf = 0; nf < 4; ++nf) s[nf] = z4;
#pragma unroll
    for (int ks = 0; ks < 6; ++ks){
      const int t = BI[ks];
      const int kb = (t >= 2 ? KL0 : KH0) + buf * 4096;
      const int cb = (t & 1) * 4 + g;
      bf16x8 b4[4];
#pragma unroll
      for (int nf = 0; nf < 4; ++nf)
        b4[nf] = tread(kb, nf * 16 + cl, cb);
#pragma unroll
      for (int nf = 0; nf < 4; ++nf)
        s[nf] = __builtin_amdgcn_mfma_f32_16x16x32_bf16(aq[AI[ks]], b4[nf], s[nf], 0, 0, 0);
    }

    // -------- fragment-ordered bias: two 16B loads per thread --------
    {
      const u16* bp = bias_base + ((jt * 64 + lane) << 4);
      u16x8 b0 = *(const u16x8*)(bp);
      u16x8 b1 = *(const u16x8*)(bp + 8);
#pragma unroll
      for (int r = 0; r < 4; ++r){
        s[0][r] += bf2f(b0[r]);
        s[1][r] += bf2f(b0[4 + r]);
        s[2][r] += bf2f(b1[r]);
        s[3][r] += bf2f(b1[4 + r]);
      }
    }

    // -------- online softmax with defer-max (T13, THR=8) --------
    float mx4[4];
    float need = -1e30f;
#pragma unroll
    for (int r = 0; r < 4; ++r){
      float mx = fmaxf(fmaxf(s[0][r], s[1][r]), fmaxf(s[2][r], s[3][r]));
      mx = fmaxf(mx, __shfl_xor(mx, 1));
      mx = fmaxf(mx, __shfl_xor(mx, 2));
      mx = fmaxf(mx, __shfl_xor(mx, 4));
      mx = fmaxf(mx, __shfl_xor(mx, 8));
      mx4[r] = mx;
      need = fmaxf(need, mx - m_run[r]);
    }
    if (__any(need > 8.f)){
      // full rescale pass (wave-uniform branch)
#pragma unroll
      for (int r = 0; r < 4; ++r){
        float mn = fmaxf(m_run[r], mx4[r]);
        float fs = __expf(m_run[r] - mn);
        m_run[r] = mn;
        l_run[r] *= fs;
#pragma unroll
        for (int nd = 0; nd < 4; ++nd) o[nd][r] *= fs;
      }
    }
#pragma unroll
    for (int r = 0; r < 4; ++r){
      float rs = 0.f;
#pragma unroll
      for (int nf = 0; nf < 4; ++nf){
        float p = __expf(s[nf][r] - m_run[r]);
        s[nf][r] = p;
        rs += p;
      }
      rs += __shfl_xor(rs, 1);
      rs += __shfl_xor(rs, 2);
      rs += __shfl_xor(rs, 4);
      rs += __shfl_xor(rs, 8);
      l_run[r] += rs;
    }
#pragma unroll
    for (int nf = 0; nf < 4; ++nf)
#pragma unroll
      for (int r = 0; r < 4; ++r){
        int off = (w * 16 + g * 4 + r) * 128 + (nf * 16 + cl) * 2;
        *(u16*)((char*)&lds[PS] + swz<7>(off)) = f2bf(s[nf][r]);
      }

    bf16x8 pa[2];
    {
      int row = (w * 16 + cl) * 128;
      pa[0] = *(const bf16x8*)((char*)&lds[PS] + swz<7>(row + (g * 8) * 2));
      pa[1] = *(const bf16x8*)((char*)&lds[PS] + swz<7>(row + (32 + g * 8) * 2));
    }
#pragma unroll
    for (int ks = 0; ks < 4; ++ks){
      const int vb = (ks < 2 ? VH0 : VL0) + buf * 4096;
      const int cb = (ks & 1) * 4 + g;
      bf16x8 b4[4];
#pragma unroll
      for (int nd = 0; nd < 4; ++nd)
        b4[nd] = tread(vb, nd * 16 + cl, cb);
#pragma unroll
      for (int nd = 0; nd < 4; ++nd)
        o[nd] = __builtin_amdgcn_mfma_f32_16x16x32_bf16(pa[ks & 1], b4[nd], o[nd], 0, 0, 0);
    }
    buf ^= 1;
  }

  __syncthreads();
#pragma unroll
  for (int r = 0; r < 4; ++r){
    float inv = 1.f / l_run[r];
    int row = w * 16 + g * 4 + r;
#pragma unroll
    for (int nd = 0; nd < 4; ++nd){
      u16 hi, lo; split2(o[nd][r] * inv, hi, lo);
      int off = row * 128 + (nd * 16 + cl) * 2;
      *(u16*)((char*)&lds[PS]  + swz<7>(off)) = hi;
      *(u16*)((char*)&lds[KH0] + swz<7>(off)) = lo;
    }
  }
  __syncthreads();
#pragma unroll
  for (int i = 0; i < 2; ++i){
    int s = tid + i * 256;
    int qr = s >> 3;
    int seg = s & 7;
    int off = qr * 128 + seg * 16;
    size_t gb = ((size_t)b * 1024 + qt * 64 + qr) * 768 + h * 64 + seg * 8;
    *(float4*)(Ohi + gb) = *(const float4*)((char*)&lds[PS]  + swz<7>(off));
    *(float4*)(Olo + gb) = *(const float4*)((char*)&lds[KH0] + swz<7>(off));
  }
}

// ---------------------------------------------------------------------------
extern "C" void kernel_launch(void* const* d_in, const int* in_sizes, int n_in,
                              void* d_out, int out_size, void* d_ws, size_t ws_size,
                              hipStream_t stream)
{
  const float* x      = (const float*)d_in[0];
  const float* qkv_w  = (const float*)d_in[1];
  const float* q_bias = (const float*)d_in[2];
  const float* v_bias = (const float*)d_in[3];
  const float* table  = (const float*)d_in[4];
  const float* proj_w = (const float*)d_in[5];
  const float* proj_b = (const float*)d_in[6];
  const int*   relidx = (const int*)d_in[7];
  float* out = (float*)d_out;

  char* ws = (char*)d_ws;
  size_t off = 0;
  auto alloc = [&](size_t nelem) -> u16* {
    u16* p = (u16*)(ws + off);
    off += (nelem * 2 + 255) & ~(size_t)255;
    return p;
  };
  u16* Xhi  = alloc((size_t)8192 * 768);
  u16* Xlo  = alloc((size_t)8192 * 768);
  u16* Whi  = alloc((size_t)2304 * 768);
  u16* Wlo  = alloc((size_t)2304 * 768);
  u16* PWhi = alloc((size_t)768 * 768);
  u16* PWlo = alloc((size_t)768 * 768);
  u16* QKhi = alloc((size_t)8192 * 1536);
  u16* QKlo = alloc((size_t)8192 * 1536);
  u16* Vthi = alloc((size_t)8 * 12 * 64 * 1024);
  u16* Vtlo = alloc((size_t)8 * 12 * 64 * 1024);
  u16* Bias = alloc((size_t)12 * 1024 * 1024);
  // O reuses X space (X consumed by QKV GEMM before attention writes O)
  u16* Ohi = Xhi;
  u16* Olo = Xlo;

  k_split3<<<8448, 256, 0, stream>>>(x, Xhi, Xlo, qkv_w, Whi, Wlo, proj_w, PWhi, PWlo);
  k_bias<<<dim3(64, 16), 256, 0, stream>>>(relidx, table, Bias);

  k_g256<<<dim3(9, 32), 512, 131072, stream>>>(
      Xhi, Xhi, Xlo, Whi, Wlo, Whi,
      q_bias, v_bias,
      QKhi, QKlo, Vthi, Vtlo);

  k_attn<<<dim3(16, 8, 12), 256, 0, stream>>>(
      QKhi, QKlo, Vthi, Vtlo, Bias, Ohi, Olo);

  k_proj<<<dim3(6, 64), 256, 0, stream>>>(
      Ohi, Ohi, Olo, PWhi, PWlo, PWhi,
      proj_b, out);
}